// Round 1
// baseline (2867.515 us; speedup 1.0000x reference)
//
#include <hip/hip_runtime.h>
#include <cstdint>
#include <cstddef>

#define N_NODES_C  100000
#define N_EDGES_C  1600000
#define N_GRAPHS_C 256
#define HID_C      128
// 1/sqrt(1+1e-5)
#define BN_SCALE_C 0.9999950000374997f

// ---------------------------------------------------------------------------
// Edge kernel: for each edge e, each thread owns one output feature f.
//   ea[f]  = eb[f] + sum_k edge_attr[e][k] * ew[k][f]   (ew column f in regs)
//   msg    = relu(h[src][f] + ea[f])
//   atomicAdd(agg[dst][f], msg)
// DIN = 64 (layer 0) or 128 (layers 1,2). blockDim = 256 -> 256/DIN edges/iter.
// ---------------------------------------------------------------------------
template<int DIN>
__global__ __launch_bounds__(256) void edge_kernel(
    const float* __restrict__ h, const float* __restrict__ edge_attr,
    const int* __restrict__ src, const int* __restrict__ dst,
    const float* __restrict__ ew, const float* __restrict__ eb,
    float* __restrict__ agg, int n_edges)
{
    const int f = threadIdx.x & (DIN - 1);
    const int g = threadIdx.x / DIN;
    constexpr int GPB = 256 / DIN;   // edge groups per block

    // ew column f resident in registers for the whole kernel
    float ewr[16];
#pragma unroll
    for (int k = 0; k < 16; ++k) ewr[k] = ew[k * DIN + f];
    const float ebr = eb[f];

    for (int e = blockIdx.x * GPB + g; e < n_edges; e += gridDim.x * GPB) {
        const int sn = src[e];
        const int dn = dst[e];
        const float4* ea4 = (const float4*)(edge_attr + (size_t)e * 16);
        float4 q0 = ea4[0], q1 = ea4[1], q2 = ea4[2], q3 = ea4[3];
        float ea[16] = {q0.x, q0.y, q0.z, q0.w,
                        q1.x, q1.y, q1.z, q1.w,
                        q2.x, q2.y, q2.z, q2.w,
                        q3.x, q3.y, q3.z, q3.w};
        float acc = ebr;
#pragma unroll
        for (int k = 0; k < 16; ++k) acc = fmaf(ea[k], ewr[k], acc);
        float msg = acc + h[(size_t)sn * DIN + f];
        msg = fmaxf(msg, 0.f);
        atomicAdd(agg + (size_t)dn * DIN + f, msg);
    }
}

// ---------------------------------------------------------------------------
// Node kernel: hh = h + agg; t = relu(g*((hh@w1 + b1)*BN_SCALE) + bt);
//              hout = relu(t@w2 + b2)
// blockDim 256 = 2 groups x 128 threads. Each group processes 16 nodes/tile.
// Weights live in LDS (stride-1 reads across f -> conflict-free).
// hh tile is stored transposed (s_x[g][k][n], stride 20 so float4 broadcast
// reads are 16B-aligned). 16 accumulators/thread -> 16 FMA per LDS w-read.
// ---------------------------------------------------------------------------
template<int DIN>
__global__ __launch_bounds__(256) void node_kernel(
    const float* __restrict__ h, const float* __restrict__ agg,
    const float* __restrict__ w1, const float* __restrict__ b1,
    const float* __restrict__ gm, const float* __restrict__ bt,
    const float* __restrict__ w2, const float* __restrict__ b2,
    float* __restrict__ hout, int n_nodes)
{
    __shared__ float s_w1[DIN * HID_C];
    __shared__ float s_w2[HID_C * HID_C];
    __shared__ float s_x[2][HID_C][20];
    __shared__ float s_b1[HID_C], s_g[HID_C], s_bt[HID_C], s_b2[HID_C];

    for (int i = threadIdx.x; i < DIN * HID_C; i += 256) s_w1[i] = w1[i];
    for (int i = threadIdx.x; i < HID_C * HID_C; i += 256) s_w2[i] = w2[i];
    if (threadIdx.x < HID_C) {
        s_b1[threadIdx.x] = b1[threadIdx.x];
        s_g [threadIdx.x] = gm[threadIdx.x];
        s_bt[threadIdx.x] = bt[threadIdx.x];
        s_b2[threadIdx.x] = b2[threadIdx.x];
    }
    __syncthreads();

    const int f = threadIdx.x & (HID_C - 1);
    const int g = threadIdx.x >> 7;

    for (int base = blockIdx.x * 32; base < n_nodes; base += gridDim.x * 32) {
        const int n0 = base + g * 16;
        // ---- load hh tile, transposed ----
        if (f < DIN) {
#pragma unroll
            for (int n = 0; n < 16; ++n) {
                const int node = n0 + n;
                float v = 0.f;
                if (node < n_nodes)
                    v = h[(size_t)node * DIN + f] + agg[(size_t)node * DIN + f];
                s_x[g][f][n] = v;
            }
        }
        __syncthreads();

        // ---- mm1: t[f] = relu(g*((dot + b1)*s) + bt) ----
        float acc[16];
#pragma unroll
        for (int n = 0; n < 16; ++n) acc[n] = s_b1[f];
#pragma unroll 4
        for (int k = 0; k < DIN; ++k) {
            const float wv = s_w1[k * HID_C + f];
            const float4* row = (const float4*)&s_x[g][k][0];
            float4 a0 = row[0], a1 = row[1], a2 = row[2], a3 = row[3];
            acc[0]  = fmaf(a0.x, wv, acc[0]);
            acc[1]  = fmaf(a0.y, wv, acc[1]);
            acc[2]  = fmaf(a0.z, wv, acc[2]);
            acc[3]  = fmaf(a0.w, wv, acc[3]);
            acc[4]  = fmaf(a1.x, wv, acc[4]);
            acc[5]  = fmaf(a1.y, wv, acc[5]);
            acc[6]  = fmaf(a1.z, wv, acc[6]);
            acc[7]  = fmaf(a1.w, wv, acc[7]);
            acc[8]  = fmaf(a2.x, wv, acc[8]);
            acc[9]  = fmaf(a2.y, wv, acc[9]);
            acc[10] = fmaf(a2.z, wv, acc[10]);
            acc[11] = fmaf(a2.w, wv, acc[11]);
            acc[12] = fmaf(a3.x, wv, acc[12]);
            acc[13] = fmaf(a3.y, wv, acc[13]);
            acc[14] = fmaf(a3.z, wv, acc[14]);
            acc[15] = fmaf(a3.w, wv, acc[15]);
        }
        {
            const float gv = s_g[f], btv = s_bt[f];
#pragma unroll
            for (int n = 0; n < 16; ++n)
                acc[n] = fmaxf(fmaf(acc[n] * BN_SCALE_C, gv, btv), 0.f);
        }
        __syncthreads();   // everyone done reading s_x (mm1) before overwrite
#pragma unroll
        for (int n = 0; n < 16; ++n) s_x[g][f][n] = acc[n];
        __syncthreads();

        // ---- mm2: hout = relu(t@w2 + b2) ----
#pragma unroll
        for (int n = 0; n < 16; ++n) acc[n] = s_b2[f];
#pragma unroll 4
        for (int k = 0; k < HID_C; ++k) {
            const float wv = s_w2[k * HID_C + f];
            const float4* row = (const float4*)&s_x[g][k][0];
            float4 a0 = row[0], a1 = row[1], a2 = row[2], a3 = row[3];
            acc[0]  = fmaf(a0.x, wv, acc[0]);
            acc[1]  = fmaf(a0.y, wv, acc[1]);
            acc[2]  = fmaf(a0.z, wv, acc[2]);
            acc[3]  = fmaf(a0.w, wv, acc[3]);
            acc[4]  = fmaf(a1.x, wv, acc[4]);
            acc[5]  = fmaf(a1.y, wv, acc[5]);
            acc[6]  = fmaf(a1.z, wv, acc[6]);
            acc[7]  = fmaf(a1.w, wv, acc[7]);
            acc[8]  = fmaf(a2.x, wv, acc[8]);
            acc[9]  = fmaf(a2.y, wv, acc[9]);
            acc[10] = fmaf(a2.z, wv, acc[10]);
            acc[11] = fmaf(a2.w, wv, acc[11]);
            acc[12] = fmaf(a3.x, wv, acc[12]);
            acc[13] = fmaf(a3.y, wv, acc[13]);
            acc[14] = fmaf(a3.z, wv, acc[14]);
            acc[15] = fmaf(a3.w, wv, acc[15]);
        }
#pragma unroll
        for (int n = 0; n < 16; ++n) {
            const int node = n0 + n;
            if (node < n_nodes)
                hout[(size_t)node * HID_C + f] = fmaxf(acc[n], 0.f);
        }
        __syncthreads();   // protect s_x before next tile's load
    }
}

// ---------------------------------------------------------------------------
// Pool + output MLP. batch is sorted -> binary search the node range per
// graph; 256 threads = 2 node-lanes x 128 features; then two 128x128 matvecs.
// ---------------------------------------------------------------------------
__global__ __launch_bounds__(256) void pool_kernel(
    const float* __restrict__ hfin, const int* __restrict__ batch,
    const float* __restrict__ w1, const float* __restrict__ b1,
    const float* __restrict__ w2, const float* __restrict__ b2,
    float* __restrict__ out, int n_nodes)
{
    const int gid = blockIdx.x;

    int lo = 0, hi = n_nodes;
    while (lo < hi) { int mid = (lo + hi) >> 1; if (batch[mid] < gid) lo = mid + 1; else hi = mid; }
    const int start = lo;
    hi = n_nodes;
    while (lo < hi) { int mid = (lo + hi) >> 1; if (batch[mid] < gid + 1) lo = mid + 1; else hi = mid; }
    const int end = lo;

    const int f = threadIdx.x & (HID_C - 1);
    const int half = threadIdx.x >> 7;

    float sum = 0.f;
    for (int n = start + half; n < end; n += 2)
        sum += hfin[(size_t)n * HID_C + f];

    __shared__ float s_sum[2][HID_C];
    __shared__ float s_p[HID_C];
    __shared__ float s_t[HID_C];
    s_sum[half][f] = sum;
    __syncthreads();

    if (threadIdx.x < HID_C) {
        const float cnt = (float)(end - start);
        s_p[f] = (s_sum[0][f] + s_sum[1][f]) / fmaxf(cnt, 1.f);
    }
    __syncthreads();

    if (threadIdx.x < HID_C) {
        float acc = b1[f];
        for (int k = 0; k < HID_C; ++k) acc = fmaf(s_p[k], w1[k * HID_C + f], acc);
        s_t[f] = fmaxf(acc, 0.f);
    }
    __syncthreads();

    if (threadIdx.x < HID_C) {
        float acc = b2[f];
        for (int k = 0; k < HID_C; ++k) acc = fmaf(s_t[k], w2[k * HID_C + f], acc);
        out[(size_t)gid * HID_C + f] = acc;
    }
}

// ---------------------------------------------------------------------------
extern "C" void kernel_launch(void* const* d_in, const int* in_sizes, int n_in,
                              void* d_out, int out_size, void* d_ws, size_t ws_size,
                              hipStream_t stream)
{
    const float* x         = (const float*)d_in[0];
    const float* edge_attr = (const float*)d_in[1];
    const int*   edge_index= (const int*)  d_in[2];
    const int*   batch     = (const int*)  d_in[3];
    const int*   src = edge_index;
    const int*   dst = edge_index + N_EDGES_C;

    const float* el_w[3] = {(const float*)d_in[4],  (const float*)d_in[12], (const float*)d_in[20]};
    const float* el_b[3] = {(const float*)d_in[5],  (const float*)d_in[13], (const float*)d_in[21]};
    const float* c_w1[3] = {(const float*)d_in[6],  (const float*)d_in[14], (const float*)d_in[22]};
    const float* c_b1[3] = {(const float*)d_in[7],  (const float*)d_in[15], (const float*)d_in[23]};
    const float* c_g [3] = {(const float*)d_in[8],  (const float*)d_in[16], (const float*)d_in[24]};
    const float* c_bt[3] = {(const float*)d_in[9],  (const float*)d_in[17], (const float*)d_in[25]};
    const float* c_w2[3] = {(const float*)d_in[10], (const float*)d_in[18], (const float*)d_in[26]};
    const float* c_b2[3] = {(const float*)d_in[11], (const float*)d_in[19], (const float*)d_in[27]};
    const float* o_w1 = (const float*)d_in[28];
    const float* o_b1 = (const float*)d_in[29];
    const float* o_w2 = (const float*)d_in[30];
    const float* o_b2 = (const float*)d_in[31];

    float* h   = (float*)d_ws;                       // N_NODES * 128 f32
    float* agg = h + (size_t)N_NODES_C * HID_C;      // N_NODES * 128 f32

    // ---- layer 0 (DIN=64, h = x input) ----
    hipMemsetAsync(agg, 0, (size_t)N_NODES_C * 64 * sizeof(float), stream);
    edge_kernel<64><<<2048, 256, 0, stream>>>(x, edge_attr, src, dst,
                                              el_w[0], el_b[0], agg, N_EDGES_C);
    node_kernel<64><<<256, 256, 0, stream>>>(x, agg, c_w1[0], c_b1[0], c_g[0],
                                             c_bt[0], c_w2[0], c_b2[0], h, N_NODES_C);

    // ---- layers 1, 2 (DIN=128, in-place h update) ----
    for (int l = 1; l < 3; ++l) {
        hipMemsetAsync(agg, 0, (size_t)N_NODES_C * HID_C * sizeof(float), stream);
        edge_kernel<128><<<2048, 256, 0, stream>>>(h, edge_attr, src, dst,
                                                   el_w[l], el_b[l], agg, N_EDGES_C);
        node_kernel<128><<<256, 256, 0, stream>>>(h, agg, c_w1[l], c_b1[l], c_g[l],
                                                  c_bt[l], c_w2[l], c_b2[l], h, N_NODES_C);
    }

    // ---- pool + output MLP ----
    pool_kernel<<<N_GRAPHS_C, 256, 0, stream>>>(h, batch, o_w1, o_b1, o_w2, o_b2,
                                                (float*)d_out, N_NODES_C);
}

// Round 2
// 2352.202 us; speedup vs baseline: 1.2191x; 1.2191x over previous
//
#include <hip/hip_runtime.h>
#include <cstdint>
#include <cstddef>

#define N_NODES_C  100000
#define N_EDGES_C  1600000
#define N_GRAPHS_C 256
#define HID_C      128
// 1/sqrt(1+1e-5)
#define BN_SCALE_C 0.9999950000374997f

#define SCAN_B 1024
#define SCAN_NB ((N_NODES_C + SCAN_B - 1) / SCAN_B)   // 98

// ---------------------------------------------------------------------------
// CSR build: histogram of dst, inclusive scan, scatter edge ids.
// Built once per launch, reused by all 3 layers.
// ---------------------------------------------------------------------------
__global__ __launch_bounds__(256) void hist_kernel(
    const int* __restrict__ dst, int* __restrict__ counts, int n_edges)
{
    int e = blockIdx.x * 256 + threadIdx.x;
    if (e < n_edges) atomicAdd(&counts[dst[e]], 1);
}

__global__ __launch_bounds__(SCAN_B) void scan1_kernel(
    const int* __restrict__ counts, int* __restrict__ incl,
    int* __restrict__ blocksums, int n)
{
    __shared__ int sdata[SCAN_B];
    const int lid = threadIdx.x;
    const int i = blockIdx.x * SCAN_B + lid;
    sdata[lid] = (i < n) ? counts[i] : 0;
    __syncthreads();
#pragma unroll
    for (int off = 1; off < SCAN_B; off <<= 1) {
        int t = (lid >= off) ? sdata[lid - off] : 0;
        __syncthreads();
        sdata[lid] += t;
        __syncthreads();
    }
    if (i < n) incl[i] = sdata[lid];
    if (lid == SCAN_B - 1) blocksums[blockIdx.x] = sdata[lid];
}

__global__ void scan2_kernel(const int* __restrict__ blocksums,
                             int* __restrict__ blockoffs, int nb)
{
    if (threadIdx.x == 0 && blockIdx.x == 0) {
        int off = 0;
        for (int b = 0; b < nb; ++b) { blockoffs[b] = off; off += blocksums[b]; }
    }
}

__global__ __launch_bounds__(SCAN_B) void scan3_kernel(
    int* __restrict__ incl, const int* __restrict__ blockoffs, int n)
{
    const int i = blockIdx.x * SCAN_B + threadIdx.x;
    if (i < n) incl[i] += blockoffs[blockIdx.x];
}

__global__ __launch_bounds__(256) void initrows_kernel(
    const int* __restrict__ incl, const int* __restrict__ counts,
    int* __restrict__ rowstart, int* __restrict__ cursor, int n)
{
    const int i = blockIdx.x * 256 + threadIdx.x;
    if (i < n) {
        const int rs = incl[i] - counts[i];
        rowstart[i] = rs;
        cursor[i]   = rs;
    }
}

__global__ __launch_bounds__(256) void scatter_kernel(
    const int* __restrict__ src, const int* __restrict__ dst,
    int* __restrict__ cursor, int* __restrict__ perm_src,
    int* __restrict__ perm_eid, int n_edges)
{
    const int e = blockIdx.x * 256 + threadIdx.x;
    if (e < n_edges) {
        const int pos = atomicAdd(&cursor[dst[e]], 1);
        perm_src[pos] = src[e];
        perm_eid[pos] = e;
    }
}

// ---------------------------------------------------------------------------
// CSR aggregate: for node v, DIN threads (one per feature) walk v's in-edges,
// accumulate relu(h[src] + edge_attr@ew + eb) in a register, write agg once.
// No atomics, no memset. ew column f lives in registers.
// ---------------------------------------------------------------------------
template<int DIN>
__global__ __launch_bounds__(256) void gine_agg_kernel(
    const float* __restrict__ h, const float* __restrict__ edge_attr,
    const int* __restrict__ perm_src, const int* __restrict__ perm_eid,
    const int* __restrict__ rowstart, const int* __restrict__ rowend,
    const float* __restrict__ ew, const float* __restrict__ eb,
    float* __restrict__ agg, int n_nodes)
{
    const int f = threadIdx.x & (DIN - 1);
    const int g = threadIdx.x / DIN;
    constexpr int GPB = 256 / DIN;
    const int v = blockIdx.x * GPB + g;
    if (v >= n_nodes) return;

    float ewr[16];
#pragma unroll
    for (int k = 0; k < 16; ++k) ewr[k] = ew[k * DIN + f];
    const float ebr = eb[f];

    float acc = 0.f;
    const int s0 = rowstart[v];
    const int s1 = rowend[v];
    for (int j = s0; j < s1; ++j) {
        const int sn  = perm_src[j];
        const int eid = perm_eid[j];
        const float4* ea4 = (const float4*)(edge_attr + (size_t)eid * 16);
        float4 q0 = ea4[0], q1 = ea4[1], q2 = ea4[2], q3 = ea4[3];
        float t = ebr;
        t = fmaf(q0.x, ewr[0],  t); t = fmaf(q0.y, ewr[1],  t);
        t = fmaf(q0.z, ewr[2],  t); t = fmaf(q0.w, ewr[3],  t);
        t = fmaf(q1.x, ewr[4],  t); t = fmaf(q1.y, ewr[5],  t);
        t = fmaf(q1.z, ewr[6],  t); t = fmaf(q1.w, ewr[7],  t);
        t = fmaf(q2.x, ewr[8],  t); t = fmaf(q2.y, ewr[9],  t);
        t = fmaf(q2.z, ewr[10], t); t = fmaf(q2.w, ewr[11], t);
        t = fmaf(q3.x, ewr[12], t); t = fmaf(q3.y, ewr[13], t);
        t = fmaf(q3.z, ewr[14], t); t = fmaf(q3.w, ewr[15], t);
        acc += fmaxf(t + h[(size_t)sn * DIN + f], 0.f);
    }
    agg[(size_t)v * DIN + f] = acc;
}

// ---------------------------------------------------------------------------
// Node kernel: hh = h + agg; t = relu(g*((hh@w1 + b1)*BN_SCALE) + bt);
//              hout = relu(t@w2 + b2)   (unchanged from round 1)
// ---------------------------------------------------------------------------
template<int DIN>
__global__ __launch_bounds__(256) void node_kernel(
    const float* __restrict__ h, const float* __restrict__ agg,
    const float* __restrict__ w1, const float* __restrict__ b1,
    const float* __restrict__ gm, const float* __restrict__ bt,
    const float* __restrict__ w2, const float* __restrict__ b2,
    float* __restrict__ hout, int n_nodes)
{
    __shared__ float s_w1[DIN * HID_C];
    __shared__ float s_w2[HID_C * HID_C];
    __shared__ float s_x[2][HID_C][20];
    __shared__ float s_b1[HID_C], s_g[HID_C], s_bt[HID_C], s_b2[HID_C];

    for (int i = threadIdx.x; i < DIN * HID_C; i += 256) s_w1[i] = w1[i];
    for (int i = threadIdx.x; i < HID_C * HID_C; i += 256) s_w2[i] = w2[i];
    if (threadIdx.x < HID_C) {
        s_b1[threadIdx.x] = b1[threadIdx.x];
        s_g [threadIdx.x] = gm[threadIdx.x];
        s_bt[threadIdx.x] = bt[threadIdx.x];
        s_b2[threadIdx.x] = b2[threadIdx.x];
    }
    __syncthreads();

    const int f = threadIdx.x & (HID_C - 1);
    const int g = threadIdx.x >> 7;

    for (int base = blockIdx.x * 32; base < n_nodes; base += gridDim.x * 32) {
        const int n0 = base + g * 16;
        if (f < DIN) {
#pragma unroll
            for (int n = 0; n < 16; ++n) {
                const int node = n0 + n;
                float v = 0.f;
                if (node < n_nodes)
                    v = h[(size_t)node * DIN + f] + agg[(size_t)node * DIN + f];
                s_x[g][f][n] = v;
            }
        }
        __syncthreads();

        float acc[16];
#pragma unroll
        for (int n = 0; n < 16; ++n) acc[n] = s_b1[f];
#pragma unroll 4
        for (int k = 0; k < DIN; ++k) {
            const float wv = s_w1[k * HID_C + f];
            const float4* row = (const float4*)&s_x[g][k][0];
            float4 a0 = row[0], a1 = row[1], a2 = row[2], a3 = row[3];
            acc[0]  = fmaf(a0.x, wv, acc[0]);
            acc[1]  = fmaf(a0.y, wv, acc[1]);
            acc[2]  = fmaf(a0.z, wv, acc[2]);
            acc[3]  = fmaf(a0.w, wv, acc[3]);
            acc[4]  = fmaf(a1.x, wv, acc[4]);
            acc[5]  = fmaf(a1.y, wv, acc[5]);
            acc[6]  = fmaf(a1.z, wv, acc[6]);
            acc[7]  = fmaf(a1.w, wv, acc[7]);
            acc[8]  = fmaf(a2.x, wv, acc[8]);
            acc[9]  = fmaf(a2.y, wv, acc[9]);
            acc[10] = fmaf(a2.z, wv, acc[10]);
            acc[11] = fmaf(a2.w, wv, acc[11]);
            acc[12] = fmaf(a3.x, wv, acc[12]);
            acc[13] = fmaf(a3.y, wv, acc[13]);
            acc[14] = fmaf(a3.z, wv, acc[14]);
            acc[15] = fmaf(a3.w, wv, acc[15]);
        }
        {
            const float gv = s_g[f], btv = s_bt[f];
#pragma unroll
            for (int n = 0; n < 16; ++n)
                acc[n] = fmaxf(fmaf(acc[n] * BN_SCALE_C, gv, btv), 0.f);
        }
        __syncthreads();
#pragma unroll
        for (int n = 0; n < 16; ++n) s_x[g][f][n] = acc[n];
        __syncthreads();

#pragma unroll
        for (int n = 0; n < 16; ++n) acc[n] = s_b2[f];
#pragma unroll 4
        for (int k = 0; k < HID_C; ++k) {
            const float wv = s_w2[k * HID_C + f];
            const float4* row = (const float4*)&s_x[g][k][0];
            float4 a0 = row[0], a1 = row[1], a2 = row[2], a3 = row[3];
            acc[0]  = fmaf(a0.x, wv, acc[0]);
            acc[1]  = fmaf(a0.y, wv, acc[1]);
            acc[2]  = fmaf(a0.z, wv, acc[2]);
            acc[3]  = fmaf(a0.w, wv, acc[3]);
            acc[4]  = fmaf(a1.x, wv, acc[4]);
            acc[5]  = fmaf(a1.y, wv, acc[5]);
            acc[6]  = fmaf(a1.z, wv, acc[6]);
            acc[7]  = fmaf(a1.w, wv, acc[7]);
            acc[8]  = fmaf(a2.x, wv, acc[8]);
            acc[9]  = fmaf(a2.y, wv, acc[9]);
            acc[10] = fmaf(a2.z, wv, acc[10]);
            acc[11] = fmaf(a2.w, wv, acc[11]);
            acc[12] = fmaf(a3.x, wv, acc[12]);
            acc[13] = fmaf(a3.y, wv, acc[13]);
            acc[14] = fmaf(a3.z, wv, acc[14]);
            acc[15] = fmaf(a3.w, wv, acc[15]);
        }
#pragma unroll
        for (int n = 0; n < 16; ++n) {
            const int node = n0 + n;
            if (node < n_nodes)
                hout[(size_t)node * HID_C + f] = fmaxf(acc[n], 0.f);
        }
        __syncthreads();
    }
}

// ---------------------------------------------------------------------------
// Pool + output MLP (unchanged).
// ---------------------------------------------------------------------------
__global__ __launch_bounds__(256) void pool_kernel(
    const float* __restrict__ hfin, const int* __restrict__ batch,
    const float* __restrict__ w1, const float* __restrict__ b1,
    const float* __restrict__ w2, const float* __restrict__ b2,
    float* __restrict__ out, int n_nodes)
{
    const int gid = blockIdx.x;

    int lo = 0, hi = n_nodes;
    while (lo < hi) { int mid = (lo + hi) >> 1; if (batch[mid] < gid) lo = mid + 1; else hi = mid; }
    const int start = lo;
    hi = n_nodes;
    while (lo < hi) { int mid = (lo + hi) >> 1; if (batch[mid] < gid + 1) lo = mid + 1; else hi = mid; }
    const int end = lo;

    const int f = threadIdx.x & (HID_C - 1);
    const int half = threadIdx.x >> 7;

    float sum = 0.f;
    for (int n = start + half; n < end; n += 2)
        sum += hfin[(size_t)n * HID_C + f];

    __shared__ float s_sum[2][HID_C];
    __shared__ float s_p[HID_C];
    __shared__ float s_t[HID_C];
    s_sum[half][f] = sum;
    __syncthreads();

    if (threadIdx.x < HID_C) {
        const float cnt = (float)(end - start);
        s_p[f] = (s_sum[0][f] + s_sum[1][f]) / fmaxf(cnt, 1.f);
    }
    __syncthreads();

    if (threadIdx.x < HID_C) {
        float acc = b1[f];
        for (int k = 0; k < HID_C; ++k) acc = fmaf(s_p[k], w1[k * HID_C + f], acc);
        s_t[f] = fmaxf(acc, 0.f);
    }
    __syncthreads();

    if (threadIdx.x < HID_C) {
        float acc = b2[f];
        for (int k = 0; k < HID_C; ++k) acc = fmaf(s_t[k], w2[k * HID_C + f], acc);
        out[(size_t)gid * HID_C + f] = acc;
    }
}

// ---------------------------------------------------------------------------
extern "C" void kernel_launch(void* const* d_in, const int* in_sizes, int n_in,
                              void* d_out, int out_size, void* d_ws, size_t ws_size,
                              hipStream_t stream)
{
    const float* x         = (const float*)d_in[0];
    const float* edge_attr = (const float*)d_in[1];
    const int*   edge_index= (const int*)  d_in[2];
    const int*   batch     = (const int*)  d_in[3];
    const int*   src = edge_index;
    const int*   dst = edge_index + N_EDGES_C;

    const float* el_w[3] = {(const float*)d_in[4],  (const float*)d_in[12], (const float*)d_in[20]};
    const float* el_b[3] = {(const float*)d_in[5],  (const float*)d_in[13], (const float*)d_in[21]};
    const float* c_w1[3] = {(const float*)d_in[6],  (const float*)d_in[14], (const float*)d_in[22]};
    const float* c_b1[3] = {(const float*)d_in[7],  (const float*)d_in[15], (const float*)d_in[23]};
    const float* c_g [3] = {(const float*)d_in[8],  (const float*)d_in[16], (const float*)d_in[24]};
    const float* c_bt[3] = {(const float*)d_in[9],  (const float*)d_in[17], (const float*)d_in[25]};
    const float* c_w2[3] = {(const float*)d_in[10], (const float*)d_in[18], (const float*)d_in[26]};
    const float* c_b2[3] = {(const float*)d_in[11], (const float*)d_in[19], (const float*)d_in[27]};
    const float* o_w1 = (const float*)d_in[28];
    const float* o_b1 = (const float*)d_in[29];
    const float* o_w2 = (const float*)d_in[30];
    const float* o_b2 = (const float*)d_in[31];

    // ---- workspace layout ----
    char* ws = (char*)d_ws;
    float* h        = (float*)ws;                               ws += (size_t)N_NODES_C * HID_C * 4;
    float* agg      = (float*)ws;                               ws += (size_t)N_NODES_C * HID_C * 4;
    int*   counts   = (int*)ws;                                 ws += (size_t)N_NODES_C * 4;
    int*   incl     = (int*)ws;                                 ws += (size_t)N_NODES_C * 4;
    int*   rowstart = (int*)ws;                                 ws += (size_t)N_NODES_C * 4;
    int*   cursor   = (int*)ws;                                 ws += (size_t)N_NODES_C * 4;
    int*   blocksums= (int*)ws;                                 ws += 128 * 4;
    int*   blockoffs= (int*)ws;                                 ws += 128 * 4;
    int*   perm_src = (int*)ws;                                 ws += (size_t)N_EDGES_C * 4;
    int*   perm_eid = (int*)ws;                                 ws += (size_t)N_EDGES_C * 4;

    // ---- CSR build (once; reused by all 3 layers) ----
    hipMemsetAsync(counts, 0, (size_t)N_NODES_C * 4, stream);
    hist_kernel<<<(N_EDGES_C + 255) / 256, 256, 0, stream>>>(dst, counts, N_EDGES_C);
    scan1_kernel<<<SCAN_NB, SCAN_B, 0, stream>>>(counts, incl, blocksums, N_NODES_C);
    scan2_kernel<<<1, 64, 0, stream>>>(blocksums, blockoffs, SCAN_NB);
    scan3_kernel<<<SCAN_NB, SCAN_B, 0, stream>>>(incl, blockoffs, N_NODES_C);
    initrows_kernel<<<(N_NODES_C + 255) / 256, 256, 0, stream>>>(incl, counts, rowstart,
                                                                 cursor, N_NODES_C);
    scatter_kernel<<<(N_EDGES_C + 255) / 256, 256, 0, stream>>>(src, dst, cursor,
                                                                perm_src, perm_eid, N_EDGES_C);

    // ---- layer 0 (DIN=64, h input = x) ----
    gine_agg_kernel<64><<<(N_NODES_C + 3) / 4, 256, 0, stream>>>(
        x, edge_attr, perm_src, perm_eid, rowstart, incl,
        el_w[0], el_b[0], agg, N_NODES_C);
    node_kernel<64><<<256, 256, 0, stream>>>(x, agg, c_w1[0], c_b1[0], c_g[0],
                                             c_bt[0], c_w2[0], c_b2[0], h, N_NODES_C);

    // ---- layers 1, 2 (DIN=128) ----
    for (int l = 1; l < 3; ++l) {
        gine_agg_kernel<128><<<(N_NODES_C + 1) / 2, 256, 0, stream>>>(
            h, edge_attr, perm_src, perm_eid, rowstart, incl,
            el_w[l], el_b[l], agg, N_NODES_C);
        node_kernel<128><<<256, 256, 0, stream>>>(h, agg, c_w1[l], c_b1[l], c_g[l],
                                                  c_bt[l], c_w2[l], c_b2[l], h, N_NODES_C);
    }

    // ---- pool + output MLP ----
    pool_kernel<<<N_GRAPHS_C, 256, 0, stream>>>(h, batch, o_w1, o_b1, o_w2, o_b2,
                                                (float*)d_out, N_NODES_C);
}

// Round 3
// 1942.910 us; speedup vs baseline: 1.4759x; 1.2107x over previous
//
#include <hip/hip_runtime.h>
#include <cstdint>
#include <cstddef>

#define N_NODES_C  100000
#define N_EDGES_C  1600000
#define N_GRAPHS_C 256
#define HID_C      128
// 1/sqrt(1+1e-5)
#define BN_SCALE_C 0.9999950000374997f

#define SCAN_B 1024
#define SCAN_NB ((N_NODES_C + SCAN_B - 1) / SCAN_B)   // 98

// ---------------------------------------------------------------------------
// CSR build: histogram of dst, inclusive scan, scatter edge ids.
// ---------------------------------------------------------------------------
__global__ __launch_bounds__(256) void hist_kernel(
    const int* __restrict__ dst, int* __restrict__ counts, int n_edges)
{
    int e = blockIdx.x * 256 + threadIdx.x;
    if (e < n_edges) atomicAdd(&counts[dst[e]], 1);
}

__global__ __launch_bounds__(SCAN_B) void scan1_kernel(
    const int* __restrict__ counts, int* __restrict__ incl,
    int* __restrict__ blocksums, int n)
{
    __shared__ int sdata[SCAN_B];
    const int lid = threadIdx.x;
    const int i = blockIdx.x * SCAN_B + lid;
    sdata[lid] = (i < n) ? counts[i] : 0;
    __syncthreads();
#pragma unroll
    for (int off = 1; off < SCAN_B; off <<= 1) {
        int t = (lid >= off) ? sdata[lid - off] : 0;
        __syncthreads();
        sdata[lid] += t;
        __syncthreads();
    }
    if (i < n) incl[i] = sdata[lid];
    if (lid == SCAN_B - 1) blocksums[blockIdx.x] = sdata[lid];
}

__global__ void scan2_kernel(const int* __restrict__ blocksums,
                             int* __restrict__ blockoffs, int nb)
{
    if (threadIdx.x == 0 && blockIdx.x == 0) {
        int off = 0;
        for (int b = 0; b < nb; ++b) { blockoffs[b] = off; off += blocksums[b]; }
    }
}

__global__ __launch_bounds__(SCAN_B) void scan3_kernel(
    int* __restrict__ incl, const int* __restrict__ blockoffs, int n)
{
    const int i = blockIdx.x * SCAN_B + threadIdx.x;
    if (i < n) incl[i] += blockoffs[blockIdx.x];
}

__global__ __launch_bounds__(256) void initrows_kernel(
    const int* __restrict__ incl, const int* __restrict__ counts,
    int* __restrict__ rowstart, int* __restrict__ cursor, int n)
{
    const int i = blockIdx.x * 256 + threadIdx.x;
    if (i < n) {
        const int rs = incl[i] - counts[i];
        rowstart[i] = rs;
        cursor[i]   = rs;
    }
}

__global__ __launch_bounds__(256) void scatter_kernel(
    const int* __restrict__ src, const int* __restrict__ dst,
    int* __restrict__ cursor, int* __restrict__ perm_src,
    int* __restrict__ perm_eid, int n_edges)
{
    const int e = blockIdx.x * 256 + threadIdx.x;
    if (e < n_edges) {
        const int pos = atomicAdd(&cursor[dst[e]], 1);
        perm_src[pos] = src[e];
        perm_eid[pos] = e;
    }
}

// Gather edge_attr rows into CSR order: coalesced writes, random 64B reads.
__global__ __launch_bounds__(256) void permute_ea_kernel(
    const float* __restrict__ edge_attr, const int* __restrict__ perm_eid,
    float* __restrict__ ea_perm, int n_edges)
{
    const int t = blockIdx.x * 256 + threadIdx.x;
    const int j = t >> 2;          // row
    const int q = t & 3;           // float4 within row
    if (j < n_edges) {
        const int eid = perm_eid[j];
        ((float4*)(ea_perm + (size_t)j * 16))[q] =
            ((const float4*)(edge_attr + (size_t)eid * 16))[q];
    }
}

// ---------------------------------------------------------------------------
// CSR aggregate, unrolled x4: 4 h-gathers in flight per thread.
// PERM: edge attrs pre-permuted -> streaming reads.
// ---------------------------------------------------------------------------
__device__ __forceinline__ float dot16(const float4* __restrict__ p,
                                       const float* ewr, float ebr)
{
    float4 q0 = p[0], q1 = p[1], q2 = p[2], q3 = p[3];
    float t = ebr;
    t = fmaf(q0.x, ewr[0],  t); t = fmaf(q0.y, ewr[1],  t);
    t = fmaf(q0.z, ewr[2],  t); t = fmaf(q0.w, ewr[3],  t);
    t = fmaf(q1.x, ewr[4],  t); t = fmaf(q1.y, ewr[5],  t);
    t = fmaf(q1.z, ewr[6],  t); t = fmaf(q1.w, ewr[7],  t);
    t = fmaf(q2.x, ewr[8],  t); t = fmaf(q2.y, ewr[9],  t);
    t = fmaf(q2.z, ewr[10], t); t = fmaf(q2.w, ewr[11], t);
    t = fmaf(q3.x, ewr[12], t); t = fmaf(q3.y, ewr[13], t);
    t = fmaf(q3.z, ewr[14], t); t = fmaf(q3.w, ewr[15], t);
    return t;
}

template<int DIN, bool PERM>
__global__ __launch_bounds__(256) void gine_agg_kernel(
    const float* __restrict__ h, const float* __restrict__ edge_attr,
    const float* __restrict__ ea_perm,
    const int* __restrict__ perm_src, const int* __restrict__ perm_eid,
    const int* __restrict__ rowstart, const int* __restrict__ rowend,
    const float* __restrict__ ew, const float* __restrict__ eb,
    float* __restrict__ agg, int n_nodes)
{
    const int f = threadIdx.x & (DIN - 1);
    const int g = threadIdx.x / DIN;
    constexpr int GPB = 256 / DIN;
    const int v = blockIdx.x * GPB + g;
    if (v >= n_nodes) return;

    float ewr[16];
#pragma unroll
    for (int k = 0; k < 16; ++k) ewr[k] = ew[k * DIN + f];
    const float ebr = eb[f];

    float acc = 0.f;
    const int s0 = rowstart[v];
    const int s1 = rowend[v];

    int j = s0;
    for (; j + 4 <= s1; j += 4) {
        const int sn0 = perm_src[j + 0];
        const int sn1 = perm_src[j + 1];
        const int sn2 = perm_src[j + 2];
        const int sn3 = perm_src[j + 3];
        const float hv0 = h[(size_t)sn0 * DIN + f];
        const float hv1 = h[(size_t)sn1 * DIN + f];
        const float hv2 = h[(size_t)sn2 * DIN + f];
        const float hv3 = h[(size_t)sn3 * DIN + f];
        const float4 *p0, *p1, *p2, *p3;
        if (PERM) {
            p0 = (const float4*)(ea_perm + (size_t)(j + 0) * 16);
            p1 = (const float4*)(ea_perm + (size_t)(j + 1) * 16);
            p2 = (const float4*)(ea_perm + (size_t)(j + 2) * 16);
            p3 = (const float4*)(ea_perm + (size_t)(j + 3) * 16);
        } else {
            p0 = (const float4*)(edge_attr + (size_t)perm_eid[j + 0] * 16);
            p1 = (const float4*)(edge_attr + (size_t)perm_eid[j + 1] * 16);
            p2 = (const float4*)(edge_attr + (size_t)perm_eid[j + 2] * 16);
            p3 = (const float4*)(edge_attr + (size_t)perm_eid[j + 3] * 16);
        }
        const float d0 = dot16(p0, ewr, ebr);
        const float d1 = dot16(p1, ewr, ebr);
        const float d2 = dot16(p2, ewr, ebr);
        const float d3 = dot16(p3, ewr, ebr);
        acc += fmaxf(d0 + hv0, 0.f) + fmaxf(d1 + hv1, 0.f)
             + fmaxf(d2 + hv2, 0.f) + fmaxf(d3 + hv3, 0.f);
    }
    for (; j < s1; ++j) {
        const int sn = perm_src[j];
        const float hv = h[(size_t)sn * DIN + f];
        const float4* p = PERM ? (const float4*)(ea_perm + (size_t)j * 16)
                               : (const float4*)(edge_attr + (size_t)perm_eid[j] * 16);
        acc += fmaxf(dot16(p, ewr, ebr) + hv, 0.f);
    }
    agg[(size_t)v * DIN + f] = acc;
}

// ---------------------------------------------------------------------------
// Node kernel v2: register-tiled 4x4. Block = 256 threads = 8 node-quads x
// 32 feature-quads; tile = 32 nodes x 128 features. Weights read from global
// (L2-resident, broadcast); only x/t tiles in LDS (37 KB -> 4 blocks/CU).
// Per k: 1 b128 w-load (global) + 1 b128 x-load (LDS broadcast) per 16 FMA.
// Grid 3125 * 32 == 100000 exactly.
// ---------------------------------------------------------------------------
#define OUTER4(acc, xv, wv)                                              \
    do {                                                                 \
        acc[0][0] = fmaf(xv.x, wv.x, acc[0][0]);                         \
        acc[0][1] = fmaf(xv.x, wv.y, acc[0][1]);                         \
        acc[0][2] = fmaf(xv.x, wv.z, acc[0][2]);                         \
        acc[0][3] = fmaf(xv.x, wv.w, acc[0][3]);                         \
        acc[1][0] = fmaf(xv.y, wv.x, acc[1][0]);                         \
        acc[1][1] = fmaf(xv.y, wv.y, acc[1][1]);                         \
        acc[1][2] = fmaf(xv.y, wv.z, acc[1][2]);                         \
        acc[1][3] = fmaf(xv.y, wv.w, acc[1][3]);                         \
        acc[2][0] = fmaf(xv.z, wv.x, acc[2][0]);                         \
        acc[2][1] = fmaf(xv.z, wv.y, acc[2][1]);                         \
        acc[2][2] = fmaf(xv.z, wv.z, acc[2][2]);                         \
        acc[2][3] = fmaf(xv.z, wv.w, acc[2][3]);                         \
        acc[3][0] = fmaf(xv.w, wv.x, acc[3][0]);                         \
        acc[3][1] = fmaf(xv.w, wv.y, acc[3][1]);                         \
        acc[3][2] = fmaf(xv.w, wv.z, acc[3][2]);                         \
        acc[3][3] = fmaf(xv.w, wv.w, acc[3][3]);                         \
    } while (0)

template<int DIN>
__global__ __launch_bounds__(256) void node_kernel(
    const float* __restrict__ h, const float* __restrict__ agg,
    const float* __restrict__ w1, const float* __restrict__ b1,
    const float* __restrict__ gm, const float* __restrict__ bt,
    const float* __restrict__ w2, const float* __restrict__ b2,
    float* __restrict__ hout, int n_nodes)
{
    __shared__ float s_x[DIN][36];     // transposed input tile (stride 36: 16B-aligned rows, no pow2 conflicts)
    __shared__ float s_t[HID_C][36];   // transposed intermediate tile

    const int tid = threadIdx.x;
    const int fg = tid & 31;           // feature quad -> f = fg*4
    const int ng = tid >> 5;           // node quad    -> n = ng*4
    const int base = blockIdx.x * 32;

    // ---- load hh = h + agg, transposed into s_x ----
    constexpr int KQ = DIN / 4;
    for (int idx = tid; idx < 32 * KQ; idx += 256) {
        const int ni = idx / KQ;
        const int k4 = (idx - ni * KQ) * 4;
        const int node = base + ni;
        const float4 hv = *(const float4*)(h   + (size_t)node * DIN + k4);
        const float4 av = *(const float4*)(agg + (size_t)node * DIN + k4);
        s_x[k4 + 0][ni] = hv.x + av.x;
        s_x[k4 + 1][ni] = hv.y + av.y;
        s_x[k4 + 2][ni] = hv.z + av.z;
        s_x[k4 + 3][ni] = hv.w + av.w;
    }
    __syncthreads();

    // ---- mm1 + BN + relu ----
    {
        const float4 b1v = *(const float4*)(b1 + fg * 4);
        float acc[4][4];
#pragma unroll
        for (int ni = 0; ni < 4; ++ni) {
            acc[ni][0] = b1v.x; acc[ni][1] = b1v.y;
            acc[ni][2] = b1v.z; acc[ni][3] = b1v.w;
        }
#pragma unroll 4
        for (int k = 0; k < DIN; ++k) {
            const float4 wv = *(const float4*)(w1 + (size_t)k * HID_C + fg * 4);
            const float4 xv = *(const float4*)(&s_x[k][ng * 4]);
            OUTER4(acc, xv, wv);
        }
        const float4 gv  = *(const float4*)(gm + fg * 4);
        const float4 btv = *(const float4*)(bt + fg * 4);
        const float ga[4]  = {gv.x, gv.y, gv.z, gv.w};
        const float bta[4] = {btv.x, btv.y, btv.z, btv.w};
#pragma unroll
        for (int fi = 0; fi < 4; ++fi) {
            float4 tv;
            tv.x = fmaxf(fmaf(acc[0][fi] * BN_SCALE_C, ga[fi], bta[fi]), 0.f);
            tv.y = fmaxf(fmaf(acc[1][fi] * BN_SCALE_C, ga[fi], bta[fi]), 0.f);
            tv.z = fmaxf(fmaf(acc[2][fi] * BN_SCALE_C, ga[fi], bta[fi]), 0.f);
            tv.w = fmaxf(fmaf(acc[3][fi] * BN_SCALE_C, ga[fi], bta[fi]), 0.f);
            *(float4*)(&s_t[fg * 4 + fi][ng * 4]) = tv;
        }
    }
    __syncthreads();

    // ---- mm2 + relu ----
    {
        const float4 b2v = *(const float4*)(b2 + fg * 4);
        float acc[4][4];
#pragma unroll
        for (int ni = 0; ni < 4; ++ni) {
            acc[ni][0] = b2v.x; acc[ni][1] = b2v.y;
            acc[ni][2] = b2v.z; acc[ni][3] = b2v.w;
        }
#pragma unroll 4
        for (int k = 0; k < HID_C; ++k) {
            const float4 wv = *(const float4*)(w2 + (size_t)k * HID_C + fg * 4);
            const float4 xv = *(const float4*)(&s_t[k][ng * 4]);
            OUTER4(acc, xv, wv);
        }
#pragma unroll
        for (int ni = 0; ni < 4; ++ni) {
            const int node = base + ng * 4 + ni;
            float4 ov;
            ov.x = fmaxf(acc[ni][0], 0.f);
            ov.y = fmaxf(acc[ni][1], 0.f);
            ov.z = fmaxf(acc[ni][2], 0.f);
            ov.w = fmaxf(acc[ni][3], 0.f);
            *(float4*)(hout + (size_t)node * HID_C + fg * 4) = ov;
        }
    }
}

// ---------------------------------------------------------------------------
// Pool + output MLP (unchanged).
// ---------------------------------------------------------------------------
__global__ __launch_bounds__(256) void pool_kernel(
    const float* __restrict__ hfin, const int* __restrict__ batch,
    const float* __restrict__ w1, const float* __restrict__ b1,
    const float* __restrict__ w2, const float* __restrict__ b2,
    float* __restrict__ out, int n_nodes)
{
    const int gid = blockIdx.x;

    int lo = 0, hi = n_nodes;
    while (lo < hi) { int mid = (lo + hi) >> 1; if (batch[mid] < gid) lo = mid + 1; else hi = mid; }
    const int start = lo;
    hi = n_nodes;
    while (lo < hi) { int mid = (lo + hi) >> 1; if (batch[mid] < gid + 1) lo = mid + 1; else hi = mid; }
    const int end = lo;

    const int f = threadIdx.x & (HID_C - 1);
    const int half = threadIdx.x >> 7;

    float sum = 0.f;
    for (int n = start + half; n < end; n += 2)
        sum += hfin[(size_t)n * HID_C + f];

    __shared__ float s_sum[2][HID_C];
    __shared__ float s_p[HID_C];
    __shared__ float s_t[HID_C];
    s_sum[half][f] = sum;
    __syncthreads();

    if (threadIdx.x < HID_C) {
        const float cnt = (float)(end - start);
        s_p[f] = (s_sum[0][f] + s_sum[1][f]) / fmaxf(cnt, 1.f);
    }
    __syncthreads();

    if (threadIdx.x < HID_C) {
        float acc = b1[f];
        for (int k = 0; k < HID_C; ++k) acc = fmaf(s_p[k], w1[k * HID_C + f], acc);
        s_t[f] = fmaxf(acc, 0.f);
    }
    __syncthreads();

    if (threadIdx.x < HID_C) {
        float acc = b2[f];
        for (int k = 0; k < HID_C; ++k) acc = fmaf(s_t[k], w2[k * HID_C + f], acc);
        out[(size_t)gid * HID_C + f] = acc;
    }
}

// ---------------------------------------------------------------------------
extern "C" void kernel_launch(void* const* d_in, const int* in_sizes, int n_in,
                              void* d_out, int out_size, void* d_ws, size_t ws_size,
                              hipStream_t stream)
{
    const float* x         = (const float*)d_in[0];
    const float* edge_attr = (const float*)d_in[1];
    const int*   edge_index= (const int*)  d_in[2];
    const int*   batch     = (const int*)  d_in[3];
    const int*   src = edge_index;
    const int*   dst = edge_index + N_EDGES_C;

    const float* el_w[3] = {(const float*)d_in[4],  (const float*)d_in[12], (const float*)d_in[20]};
    const float* el_b[3] = {(const float*)d_in[5],  (const float*)d_in[13], (const float*)d_in[21]};
    const float* c_w1[3] = {(const float*)d_in[6],  (const float*)d_in[14], (const float*)d_in[22]};
    const float* c_b1[3] = {(const float*)d_in[7],  (const float*)d_in[15], (const float*)d_in[23]};
    const float* c_g [3] = {(const float*)d_in[8],  (const float*)d_in[16], (const float*)d_in[24]};
    const float* c_bt[3] = {(const float*)d_in[9],  (const float*)d_in[17], (const float*)d_in[25]};
    const float* c_w2[3] = {(const float*)d_in[10], (const float*)d_in[18], (const float*)d_in[26]};
    const float* c_b2[3] = {(const float*)d_in[11], (const float*)d_in[19], (const float*)d_in[27]};
    const float* o_w1 = (const float*)d_in[28];
    const float* o_b1 = (const float*)d_in[29];
    const float* o_w2 = (const float*)d_in[30];
    const float* o_b2 = (const float*)d_in[31];

    // ---- workspace layout ----
    char* wsp = (char*)d_ws;
    size_t used = 0;
    auto alloc = [&](size_t bytes) { char* p = wsp + used; used += (bytes + 255) & ~(size_t)255; return p; };
    float* h        = (float*)alloc((size_t)N_NODES_C * HID_C * 4);
    float* agg      = (float*)alloc((size_t)N_NODES_C * HID_C * 4);
    int*   counts   = (int*)alloc((size_t)N_NODES_C * 4);
    int*   incl     = (int*)alloc((size_t)N_NODES_C * 4);
    int*   rowstart = (int*)alloc((size_t)N_NODES_C * 4);
    int*   cursor   = (int*)alloc((size_t)N_NODES_C * 4);
    int*   blocksums= (int*)alloc(128 * 4);
    int*   blockoffs= (int*)alloc(128 * 4);
    int*   perm_src = (int*)alloc((size_t)N_EDGES_C * 4);
    int*   perm_eid = (int*)alloc((size_t)N_EDGES_C * 4);
    const size_t base_need = used;
    float* ea_perm  = (float*)alloc((size_t)N_EDGES_C * 16 * 4);
    const bool use_perm = (used <= ws_size);
    (void)base_need;

    // ---- CSR build (once; reused by all 3 layers) ----
    hipMemsetAsync(counts, 0, (size_t)N_NODES_C * 4, stream);
    hist_kernel<<<(N_EDGES_C + 255) / 256, 256, 0, stream>>>(dst, counts, N_EDGES_C);
    scan1_kernel<<<SCAN_NB, SCAN_B, 0, stream>>>(counts, incl, blocksums, N_NODES_C);
    scan2_kernel<<<1, 64, 0, stream>>>(blocksums, blockoffs, SCAN_NB);
    scan3_kernel<<<SCAN_NB, SCAN_B, 0, stream>>>(incl, blockoffs, N_NODES_C);
    initrows_kernel<<<(N_NODES_C + 255) / 256, 256, 0, stream>>>(incl, counts, rowstart,
                                                                 cursor, N_NODES_C);
    scatter_kernel<<<(N_EDGES_C + 255) / 256, 256, 0, stream>>>(src, dst, cursor,
                                                                perm_src, perm_eid, N_EDGES_C);
    if (use_perm)
        permute_ea_kernel<<<(N_EDGES_C * 4 + 255) / 256, 256, 0, stream>>>(
            edge_attr, perm_eid, ea_perm, N_EDGES_C);

    // ---- layer 0 (DIN=64, h input = x) ----
    if (use_perm)
        gine_agg_kernel<64, true><<<N_NODES_C / 4, 256, 0, stream>>>(
            x, edge_attr, ea_perm, perm_src, perm_eid, rowstart, incl,
            el_w[0], el_b[0], agg, N_NODES_C);
    else
        gine_agg_kernel<64, false><<<N_NODES_C / 4, 256, 0, stream>>>(
            x, edge_attr, ea_perm, perm_src, perm_eid, rowstart, incl,
            el_w[0], el_b[0], agg, N_NODES_C);
    node_kernel<64><<<N_NODES_C / 32, 256, 0, stream>>>(
        x, agg, c_w1[0], c_b1[0], c_g[0], c_bt[0], c_w2[0], c_b2[0], h, N_NODES_C);

    // ---- layers 1, 2 (DIN=128) ----
    for (int l = 1; l < 3; ++l) {
        if (use_perm)
            gine_agg_kernel<128, true><<<N_NODES_C / 2, 256, 0, stream>>>(
                h, edge_attr, ea_perm, perm_src, perm_eid, rowstart, incl,
                el_w[l], el_b[l], agg, N_NODES_C);
        else
            gine_agg_kernel<128, false><<<N_NODES_C / 2, 256, 0, stream>>>(
                h, edge_attr, ea_perm, perm_src, perm_eid, rowstart, incl,
                el_w[l], el_b[l], agg, N_NODES_C);
        node_kernel<128><<<N_NODES_C / 32, 256, 0, stream>>>(
            h, agg, c_w1[l], c_b1[l], c_g[l], c_bt[l], c_w2[l], c_b2[l], h, N_NODES_C);
    }

    // ---- pool + output MLP ----
    pool_kernel<<<N_GRAPHS_C, 256, 0, stream>>>(h, batch, o_w1, o_b1, o_w2, o_b2,
                                                (float*)d_out, N_NODES_C);
}